// Round 2
// baseline (622.702 us; speedup 1.0000x reference)
//
#include <hip/hip_runtime.h>
#include <hip/hip_bf16.h>

typedef __hip_bfloat16 bf16;

__device__ __forceinline__ float b2f(bf16 v) { return __bfloat162float(v); }
__device__ __forceinline__ bf16  f2b(float v) { return __float2bfloat16(v); }

// Problem sizes
#define BB 4
#define CC 256
#define HH 64
#define WW 64
#define HW 4096      // 64*64
#define HD 128
#define WD 128
#define HWD 16384    // 128*128
#define NG 4
#define CG 64        // channels per group

// ---------------------------------------------------------------------------
// K1: off = (conv1x1(x, w_off)+b_off) * sigmoid(conv1x1(x, w_ast)+b_ast)
// 16384 pixels, 32 output channels (x2 for off/ast interleaved -> 64 combined)
// grid: 256 blocks = 4 q-groups * 64 pixel-blocks; thread owns 16 combined out
// ---------------------------------------------------------------------------
__global__ __launch_bounds__(256) void k1_off(const float* __restrict__ x,
        const float* __restrict__ w_off, const float* __restrict__ b_off,
        const float* __restrict__ w_ast, const float* __restrict__ b_ast,
        float* __restrict__ off)
{
    __shared__ __align__(16) float sw[256 * 16];
    const int q = blockIdx.x >> 6;
    const int pix = ((blockIdx.x & 63) << 8) + threadIdx.x;
    for (int i = threadIdx.x; i < 256 * 16; i += 256) {
        int c = i >> 4, jj = i & 15;
        int j = (q << 4) + jj;
        int oc = j >> 1, kind = j & 1;
        sw[i] = kind ? w_ast[oc * 256 + c] : w_off[oc * 256 + c];
    }
    __syncthreads();
    const int b = pix >> 12, hw = pix & 4095;
    float acc[16];
#pragma unroll
    for (int m = 0; m < 16; ++m) acc[m] = 0.f;
    const float* xp = x + ((size_t)b * CC << 12) + hw;
    for (int c = 0; c < 256; ++c) {
        float xv = xp[(size_t)c << 12];
        const float4* wrow = reinterpret_cast<const float4*>(&sw[c << 4]);
#pragma unroll
        for (int m4 = 0; m4 < 4; ++m4) {
            float4 wv = wrow[m4];
            acc[m4 * 4 + 0] += xv * wv.x; acc[m4 * 4 + 1] += xv * wv.y;
            acc[m4 * 4 + 2] += xv * wv.z; acc[m4 * 4 + 3] += xv * wv.w;
        }
    }
#pragma unroll
    for (int m = 0; m < 8; ++m) {
        int oc = (q << 3) + m;
        float o = acc[2 * m]     + b_off[oc];
        float a = acc[2 * m + 1] + b_ast[oc];
        float s = 1.f / (1.f + expf(-a));
        off[((size_t)(b * 32 + oc) << 12) + hw] = o * s;
    }
}

// ---------------------------------------------------------------------------
// K2: def_sample -> x_up (bf16, (4,256,128,128))
// thread per (b,g,hy,wx), loops 64 group channels
// ix = (wx+0.5+ox)*0.5-0.5 clip[0,63]; offset ch = g*8 + (hy&1)*4 + (wx&1)*2
// ---------------------------------------------------------------------------
__global__ __launch_bounds__(256) void k2_defsample(const float* __restrict__ x,
        const float* __restrict__ off, bf16* __restrict__ xup)
{
    int t = blockIdx.x * 256 + threadIdx.x;
    int wx = t & 127, hy = (t >> 7) & 127, g = (t >> 14) & 3, b = t >> 16;
    int h = hy >> 1, w = wx >> 1;
    int och = (g << 3) + ((hy & 1) << 2) + ((wx & 1) << 1);
    float ox = off[((size_t)(b * 32 + och)     << 12) + (h << 6) + w];
    float oy = off[((size_t)(b * 32 + och + 1) << 12) + (h << 6) + w];
    float ix = (wx + 0.5f + ox) * 0.5f - 0.5f;
    float iy = (hy + 0.5f + oy) * 0.5f - 0.5f;
    ix = fminf(fmaxf(ix, 0.f), 63.f);
    iy = fminf(fmaxf(iy, 0.f), 63.f);
    float x0f = floorf(ix), y0f = floorf(iy);
    float fx = ix - x0f, fy = iy - y0f;
    int x0 = (int)x0f, y0 = (int)y0f;
    int x1 = min(x0 + 1, 63), y1 = min(y0 + 1, 63);
    float w00 = (1.f - fx) * (1.f - fy), w01 = fx * (1.f - fy);
    float w10 = (1.f - fx) * fy,        w11 = fx * fy;
    int i00 = (y0 << 6) + x0, i01 = (y0 << 6) + x1;
    int i10 = (y1 << 6) + x0, i11 = (y1 << 6) + x1;
    const float* xb = x + ((size_t)(b * CC + (g << 6)) << 12);
    bf16* ob = xup + ((size_t)(b * CC + (g << 6)) << 14) + (hy << 7) + wx;
    for (int c = 0; c < 64; ++c) {
        const float* xc = xb + ((size_t)c << 12);
        float v = w00 * xc[i00] + w01 * xc[i01]
                + w10 * xc[i10] + w11 * xc[i11];
        ob[(size_t)c << 14] = f2b(v);
    }
}

// ---------------------------------------------------------------------------
// K3: comp = conv1x1(x_up, 256->64) + bias, fp32 out (4,64,128,128)
// grid: 1024 blocks = 4 q-groups * 256 pixel-blocks; thread owns 16 outputs
// ---------------------------------------------------------------------------
__global__ __launch_bounds__(256) void k3_comp(const bf16* __restrict__ xup,
        const float* __restrict__ cw, const float* __restrict__ cb,
        float* __restrict__ comp)
{
    __shared__ __align__(16) float sw[256 * 16];
    const int q = blockIdx.x >> 8;
    const int pix = ((blockIdx.x & 255) << 8) + threadIdx.x;
    for (int i = threadIdx.x; i < 256 * 16; i += 256) {
        int c = i >> 4, jj = i & 15;
        int oc = (q << 4) + jj;
        sw[i] = cw[oc * 256 + c];
    }
    __syncthreads();
    const int b = pix >> 14, hw = pix & 16383;
    float acc[16];
#pragma unroll
    for (int m = 0; m < 16; ++m) acc[m] = 0.f;
    const bf16* xp = xup + ((size_t)b * CC << 14) + hw;
    for (int c = 0; c < 256; ++c) {
        float xv = b2f(xp[(size_t)c << 14]);
        const float4* wrow = reinterpret_cast<const float4*>(&sw[c << 4]);
#pragma unroll
        for (int m4 = 0; m4 < 4; ++m4) {
            float4 wv = wrow[m4];
            acc[m4 * 4 + 0] += xv * wv.x; acc[m4 * 4 + 1] += xv * wv.y;
            acc[m4 * 4 + 2] += xv * wv.z; acc[m4 * 4 + 3] += xv * wv.w;
        }
    }
#pragma unroll
    for (int m = 0; m < 16; ++m) {
        int oc = (q << 4) + m;
        comp[((size_t)(b * 64 + oc) << 14) + hw] = acc[m] + cb[oc];
    }
}

// ---------------------------------------------------------------------------
// K4: kern = softmax(conv1x1(comp, 64->9)+fb) fused with 3x3 dynamic filter
// thread per (b,h,w), loops 256 channels; zero-padded taps
// ---------------------------------------------------------------------------
__global__ __launch_bounds__(256) void k4_filter(const bf16* __restrict__ xup,
        const float* __restrict__ comp,
        const float* __restrict__ fw_g, const float* __restrict__ fb,
        bf16* __restrict__ xfilt)
{
    __shared__ __align__(16) float fw[64 * 12];
    for (int i = threadIdx.x; i < 64 * 12; i += 256) {
        int c = i / 12, k = i % 12;
        fw[i] = (k < 9) ? fw_g[k * 64 + c] : 0.f;
    }
    __syncthreads();
    int pix = blockIdx.x * 256 + threadIdx.x;
    int b = pix >> 14, hw = pix & 16383;
    int h = hw >> 7, w = hw & 127;
    float a[9];
#pragma unroll
    for (int k = 0; k < 9; ++k) a[k] = fb[k];
    const float* cp = comp + ((size_t)b * 64 << 14) + hw;
    for (int c = 0; c < 64; ++c) {
        float cv = cp[(size_t)c << 14];
        const float4* wr = reinterpret_cast<const float4*>(&fw[c * 12]);
        float4 w0 = wr[0], w1 = wr[1];
        float w8 = fw[c * 12 + 8];
        a[0] += cv * w0.x; a[1] += cv * w0.y; a[2] += cv * w0.z; a[3] += cv * w0.w;
        a[4] += cv * w1.x; a[5] += cv * w1.y; a[6] += cv * w1.z; a[7] += cv * w1.w;
        a[8] += cv * w8;
    }
    float mx = a[0];
#pragma unroll
    for (int k = 1; k < 9; ++k) mx = fmaxf(mx, a[k]);
    float s = 0.f;
#pragma unroll
    for (int k = 0; k < 9; ++k) { a[k] = expf(a[k] - mx); s += a[k]; }
    float inv = 1.f / s;
#pragma unroll
    for (int k = 0; k < 9; ++k) a[k] *= inv;

    const bf16* xb = xup + ((size_t)b * CC << 14);
    bf16* ob = xfilt + ((size_t)b * CC << 14) + hw;
    bool ym[3] = { h > 0, true, h < 127 };
    bool xm[3] = { w > 0, true, w < 127 };
    int yoff[3] = { (h - 1) << 7, h << 7, (h + 1) << 7 };
    int xoff[3] = { w - 1, w, w + 1 };
    for (int ch = 0; ch < 256; ++ch) {
        const bf16* xc = xb + ((size_t)ch << 14);
        float sum = 0.f;
#pragma unroll
        for (int dy = 0; dy < 3; ++dy) {
#pragma unroll
            for (int dx = 0; dx < 3; ++dx) {
                if (ym[dy] && xm[dx])
                    sum += a[dy * 3 + dx] * b2f(xc[yoff[dy] + xoff[dx]]);
            }
        }
        ob[(size_t)ch << 14] = f2b(sum);
    }
}

// ---------------------------------------------------------------------------
// K5: toff = (conv1x1(comp,64->8)+tb) * sigmoid(conv1x1(comp,64->8)+tab)
// thread per pixel, 16 combined outputs
// ---------------------------------------------------------------------------
__global__ __launch_bounds__(256) void k5_toff(const float* __restrict__ comp,
        const float* __restrict__ tw, const float* __restrict__ tb,
        const float* __restrict__ taw, const float* __restrict__ tab,
        float* __restrict__ toff)
{
    __shared__ __align__(16) float sw[64 * 16];
    for (int i = threadIdx.x; i < 64 * 16; i += 256) {
        int c = i >> 4, jj = i & 15;
        int oc = jj >> 1, kind = jj & 1;
        sw[i] = kind ? taw[oc * 64 + c] : tw[oc * 64 + c];
    }
    __syncthreads();
    int pix = blockIdx.x * 256 + threadIdx.x;
    int b = pix >> 14, hw = pix & 16383;
    float acc[16];
#pragma unroll
    for (int m = 0; m < 16; ++m) acc[m] = 0.f;
    const float* cp = comp + ((size_t)b * 64 << 14) + hw;
    for (int c = 0; c < 64; ++c) {
        float cv = cp[(size_t)c << 14];
        const float4* wr = reinterpret_cast<const float4*>(&sw[c << 4]);
#pragma unroll
        for (int m4 = 0; m4 < 4; ++m4) {
            float4 wv = wr[m4];
            acc[m4 * 4 + 0] += cv * wv.x; acc[m4 * 4 + 1] += cv * wv.y;
            acc[m4 * 4 + 2] += cv * wv.z; acc[m4 * 4 + 3] += cv * wv.w;
        }
    }
#pragma unroll
    for (int oc = 0; oc < 8; ++oc) {
        float o = acc[2 * oc]     + tb[oc];
        float a = acc[2 * oc + 1] + tab[oc];
        toff[((size_t)(b * 8 + oc) << 14) + hw] = o * (1.f / (1.f + expf(-a)));
    }
}

// ---------------------------------------------------------------------------
// K6: trim_op -> out. ix = w + ox clip[0,127]; thread per (b,g,h,w), 64 ch
// ---------------------------------------------------------------------------
__global__ __launch_bounds__(256) void k6_trim(const bf16* __restrict__ xfilt,
        const float* __restrict__ toff, float* __restrict__ out)
{
    int t = blockIdx.x * 256 + threadIdx.x;
    int w = t & 127, h = (t >> 7) & 127, g = (t >> 14) & 3, b = t >> 16;
    int hw = (h << 7) + w;
    float ox = toff[((size_t)(b * 8 + 2 * g)     << 14) + hw];
    float oy = toff[((size_t)(b * 8 + 2 * g + 1) << 14) + hw];
    float ix = fminf(fmaxf(w + ox, 0.f), 127.f);
    float iy = fminf(fmaxf(h + oy, 0.f), 127.f);
    float x0f = floorf(ix), y0f = floorf(iy);
    float fx = ix - x0f, fy = iy - y0f;
    int x0 = (int)x0f, y0 = (int)y0f;
    int x1 = min(x0 + 1, 127), y1 = min(y0 + 1, 127);
    float w00 = (1.f - fx) * (1.f - fy), w01 = fx * (1.f - fy);
    float w10 = (1.f - fx) * fy,        w11 = fx * fy;
    int i00 = (y0 << 7) + x0, i01 = (y0 << 7) + x1;
    int i10 = (y1 << 7) + x0, i11 = (y1 << 7) + x1;
    const bf16* xb = xfilt + ((size_t)(b * CC + (g << 6)) << 14);
    float* ob = out + ((size_t)(b * CC + (g << 6)) << 14) + hw;
    for (int c = 0; c < 64; ++c) {
        const bf16* xc = xb + ((size_t)c << 14);
        float v = w00 * b2f(xc[i00]) + w01 * b2f(xc[i01])
                + w10 * b2f(xc[i10]) + w11 * b2f(xc[i11]);
        ob[(size_t)c << 14] = v;
    }
}

extern "C" void kernel_launch(void* const* d_in, const int* in_sizes, int n_in,
                              void* d_out, int out_size, void* d_ws, size_t ws_size,
                              hipStream_t stream)
{
    const float* x       = (const float*)d_in[0];
    const float* w_off   = (const float*)d_in[1];
    const float* b_off   = (const float*)d_in[2];
    const float* w_ast   = (const float*)d_in[3];
    const float* b_ast   = (const float*)d_in[4];
    const float* comp_w  = (const float*)d_in[5];
    const float* comp_b  = (const float*)d_in[6];
    const float* filt_w  = (const float*)d_in[7];
    const float* filt_b  = (const float*)d_in[8];
    const float* trim_w  = (const float*)d_in[9];
    const float* trim_b  = (const float*)d_in[10];
    const float* trim_aw = (const float*)d_in[11];
    const float* trim_ab = (const float*)d_in[12];
    float* out = (float*)d_out;

    char* ws = (char*)d_ws;
    float* off   = (float*)(ws);                              // 2 MiB
    bf16*  xup   = (bf16*) (ws + (2ull << 20));               // 32 MiB
    float* comp  = (float*)(ws + (34ull << 20));              // 16 MiB
    bf16*  xfilt = (bf16*) (ws + (50ull << 20));              // 32 MiB
    float* toff  = (float*)(ws + (82ull << 20));              // 2 MiB (total 84 MiB)

    hipLaunchKernelGGL(k1_off,      dim3(256),  dim3(256), 0, stream,
                       x, w_off, b_off, w_ast, b_ast, off);
    hipLaunchKernelGGL(k2_defsample,dim3(1024), dim3(256), 0, stream,
                       x, off, xup);
    hipLaunchKernelGGL(k3_comp,     dim3(1024), dim3(256), 0, stream,
                       xup, comp_w, comp_b, comp);
    hipLaunchKernelGGL(k4_filter,   dim3(256),  dim3(256), 0, stream,
                       xup, comp, filt_w, filt_b, xfilt);
    hipLaunchKernelGGL(k5_toff,     dim3(256),  dim3(256), 0, stream,
                       comp, trim_w, trim_b, trim_aw, trim_ab, toff);
    hipLaunchKernelGGL(k6_trim,     dim3(1024), dim3(256), 0, stream,
                       xfilt, toff, out);
}

// Round 3
// 279.099 us; speedup vs baseline: 2.2311x; 2.2311x over previous
//
#include <hip/hip_runtime.h>
#include <hip/hip_bf16.h>

typedef __hip_bfloat16 bf16;

__device__ __forceinline__ float b2f(bf16 v) { return __bfloat162float(v); }
__device__ __forceinline__ bf16  f2b(float v) { return __float2bfloat16(v); }

// Problem sizes
#define BB 4
#define CC 256
#define HH 64
#define WW 64
#define HW 4096      // 64*64
#define HD 128
#define WD 128
#define HWD 16384    // 128*128
#define NG 4
#define CG 64        // channels per group

// ---------------------------------------------------------------------------
// K1: off = (conv1x1(x, w_off)+b_off) * sigmoid(conv1x1(x, w_ast)+b_ast)
// ---------------------------------------------------------------------------
__global__ __launch_bounds__(256) void k1_off(const float* __restrict__ x,
        const float* __restrict__ w_off, const float* __restrict__ b_off,
        const float* __restrict__ w_ast, const float* __restrict__ b_ast,
        float* __restrict__ off)
{
    __shared__ __align__(16) float sw[256 * 16];
    const int q = blockIdx.x >> 6;
    const int pix = ((blockIdx.x & 63) << 8) + threadIdx.x;
    for (int i = threadIdx.x; i < 256 * 16; i += 256) {
        int c = i >> 4, jj = i & 15;
        int j = (q << 4) + jj;
        int oc = j >> 1, kind = j & 1;
        sw[i] = kind ? w_ast[oc * 256 + c] : w_off[oc * 256 + c];
    }
    __syncthreads();
    const int b = pix >> 12, hw = pix & 4095;
    float acc[16];
#pragma unroll
    for (int m = 0; m < 16; ++m) acc[m] = 0.f;
    const float* xp = x + ((size_t)b * CC << 12) + hw;
    for (int c = 0; c < 256; ++c) {
        float xv = xp[(size_t)c << 12];
        const float4* wrow = reinterpret_cast<const float4*>(&sw[c << 4]);
#pragma unroll
        for (int m4 = 0; m4 < 4; ++m4) {
            float4 wv = wrow[m4];
            acc[m4 * 4 + 0] += xv * wv.x; acc[m4 * 4 + 1] += xv * wv.y;
            acc[m4 * 4 + 2] += xv * wv.z; acc[m4 * 4 + 3] += xv * wv.w;
        }
    }
#pragma unroll
    for (int m = 0; m < 8; ++m) {
        int oc = (q << 3) + m;
        float o = acc[2 * m]     + b_off[oc];
        float a = acc[2 * m + 1] + b_ast[oc];
        float s = 1.f / (1.f + expf(-a));
        off[((size_t)(b * 32 + oc) << 12) + hw] = o * s;
    }
}

// ---------------------------------------------------------------------------
// K2: def_sample -> x_up (bf16, (4,256,128,128))
// ---------------------------------------------------------------------------
__global__ __launch_bounds__(256) void k2_defsample(const float* __restrict__ x,
        const float* __restrict__ off, bf16* __restrict__ xup)
{
    int t = blockIdx.x * 256 + threadIdx.x;
    int wx = t & 127, hy = (t >> 7) & 127, g = (t >> 14) & 3, b = t >> 16;
    int h = hy >> 1, w = wx >> 1;
    int och = (g << 3) + ((hy & 1) << 2) + ((wx & 1) << 1);
    float ox = off[((size_t)(b * 32 + och)     << 12) + (h << 6) + w];
    float oy = off[((size_t)(b * 32 + och + 1) << 12) + (h << 6) + w];
    float ix = (wx + 0.5f + ox) * 0.5f - 0.5f;
    float iy = (hy + 0.5f + oy) * 0.5f - 0.5f;
    ix = fminf(fmaxf(ix, 0.f), 63.f);
    iy = fminf(fmaxf(iy, 0.f), 63.f);
    float x0f = floorf(ix), y0f = floorf(iy);
    float fx = ix - x0f, fy = iy - y0f;
    int x0 = (int)x0f, y0 = (int)y0f;
    int x1 = min(x0 + 1, 63), y1 = min(y0 + 1, 63);
    float w00 = (1.f - fx) * (1.f - fy), w01 = fx * (1.f - fy);
    float w10 = (1.f - fx) * fy,        w11 = fx * fy;
    int i00 = (y0 << 6) + x0, i01 = (y0 << 6) + x1;
    int i10 = (y1 << 6) + x0, i11 = (y1 << 6) + x1;
    const float* xb = x + ((size_t)(b * CC + (g << 6)) << 12);
    bf16* ob = xup + ((size_t)(b * CC + (g << 6)) << 14) + (hy << 7) + wx;
    for (int c = 0; c < 64; ++c) {
        const float* xc = xb + ((size_t)c << 12);
        float v = w00 * xc[i00] + w01 * xc[i01]
                + w10 * xc[i10] + w11 * xc[i11];
        ob[(size_t)c << 14] = f2b(v);
    }
}

// ---------------------------------------------------------------------------
// K3: comp = conv1x1(x_up, 256->64) + bias, fp32 out (4,64,128,128)
// ---------------------------------------------------------------------------
__global__ __launch_bounds__(256) void k3_comp(const bf16* __restrict__ xup,
        const float* __restrict__ cw, const float* __restrict__ cb,
        float* __restrict__ comp)
{
    __shared__ __align__(16) float sw[256 * 16];
    const int q = blockIdx.x >> 8;
    const int pix = ((blockIdx.x & 255) << 8) + threadIdx.x;
    for (int i = threadIdx.x; i < 256 * 16; i += 256) {
        int c = i >> 4, jj = i & 15;
        int oc = (q << 4) + jj;
        sw[i] = cw[oc * 256 + c];
    }
    __syncthreads();
    const int b = pix >> 14, hw = pix & 16383;
    float acc[16];
#pragma unroll
    for (int m = 0; m < 16; ++m) acc[m] = 0.f;
    const bf16* xp = xup + ((size_t)b * CC << 14) + hw;
    for (int c = 0; c < 256; ++c) {
        float xv = b2f(xp[(size_t)c << 14]);
        const float4* wrow = reinterpret_cast<const float4*>(&sw[c << 4]);
#pragma unroll
        for (int m4 = 0; m4 < 4; ++m4) {
            float4 wv = wrow[m4];
            acc[m4 * 4 + 0] += xv * wv.x; acc[m4 * 4 + 1] += xv * wv.y;
            acc[m4 * 4 + 2] += xv * wv.z; acc[m4 * 4 + 3] += xv * wv.w;
        }
    }
#pragma unroll
    for (int m = 0; m < 16; ++m) {
        int oc = (q << 4) + m;
        comp[((size_t)(b * 64 + oc) << 14) + hw] = acc[m] + cb[oc];
    }
}

// ---------------------------------------------------------------------------
// K4a: kern = softmax(conv1x1(comp, 64->9)+fb); store bf16 [b][9][hw]
// one thread per pixel (65536)
// ---------------------------------------------------------------------------
__global__ __launch_bounds__(256) void k4a_kern(const float* __restrict__ comp,
        const float* __restrict__ fw_g, const float* __restrict__ fb,
        bf16* __restrict__ kern)
{
    __shared__ __align__(16) float fw[64 * 12];
    for (int i = threadIdx.x; i < 64 * 12; i += 256) {
        int c = i / 12, k = i % 12;
        fw[i] = (k < 9) ? fw_g[k * 64 + c] : 0.f;
    }
    __syncthreads();
    int pix = blockIdx.x * 256 + threadIdx.x;
    int b = pix >> 14, hw = pix & 16383;
    float a[9];
#pragma unroll
    for (int k = 0; k < 9; ++k) a[k] = fb[k];
    const float* cp = comp + ((size_t)b * 64 << 14) + hw;
    for (int c = 0; c < 64; ++c) {
        float cv = cp[(size_t)c << 14];
        const float4* wr = reinterpret_cast<const float4*>(&fw[c * 12]);
        float4 w0 = wr[0], w1 = wr[1];
        float w8 = fw[c * 12 + 8];
        a[0] += cv * w0.x; a[1] += cv * w0.y; a[2] += cv * w0.z; a[3] += cv * w0.w;
        a[4] += cv * w1.x; a[5] += cv * w1.y; a[6] += cv * w1.z; a[7] += cv * w1.w;
        a[8] += cv * w8;
    }
    float mx = a[0];
#pragma unroll
    for (int k = 1; k < 9; ++k) mx = fmaxf(mx, a[k]);
    float s = 0.f;
#pragma unroll
    for (int k = 0; k < 9; ++k) { a[k] = expf(a[k] - mx); s += a[k]; }
    float inv = 1.f / s;
#pragma unroll
    for (int k = 0; k < 9; ++k)
        kern[((size_t)(b * 9 + k) << 14) + hw] = f2b(a[k] * inv);
}

// ---------------------------------------------------------------------------
// K4b: xfilt[b][ch][hw] = sum_k kern[b][k][hw] * xup[b][ch][tap_k(hw)]
// one thread per output element (16.7M); boundary via zeroed weights
// ---------------------------------------------------------------------------
__global__ __launch_bounds__(256) void k4b_apply(const bf16* __restrict__ xup,
        const bf16* __restrict__ kern, bf16* __restrict__ xfilt)
{
    int t = blockIdx.x * 256 + threadIdx.x;
    int hw = t & 16383;
    int ch = (t >> 14) & 255;
    int b  = t >> 22;
    int h = hw >> 7, w = hw & 127;

    const bf16* kp = kern + ((size_t)b * 9 << 14) + hw;
    float wk[9];
#pragma unroll
    for (int k = 0; k < 9; ++k) wk[k] = b2f(kp[(size_t)k << 14]);

    float ymask[3] = { h > 0 ? 1.f : 0.f, 1.f, h < 127 ? 1.f : 0.f };
    float xmask[3] = { w > 0 ? 1.f : 0.f, 1.f, w < 127 ? 1.f : 0.f };
    int hy[3] = { (max(h - 1, 0)) << 7, h << 7, (min(h + 1, 127)) << 7 };
    int wx[3] = { max(w - 1, 0), w, min(w + 1, 127) };

    const bf16* xc = xup + ((size_t)(b * 256 + ch) << 14);
    float sum = 0.f;
#pragma unroll
    for (int dy = 0; dy < 3; ++dy) {
#pragma unroll
        for (int dx = 0; dx < 3; ++dx) {
            float wgt = wk[dy * 3 + dx] * ymask[dy] * xmask[dx];
            sum += wgt * b2f(xc[hy[dy] + wx[dx]]);
        }
    }
    xfilt[((size_t)(b * 256 + ch) << 14) + hw] = f2b(sum);
}

// ---------------------------------------------------------------------------
// K5: toff = (conv1x1(comp,64->8)+tb) * sigmoid(conv1x1(comp,64->8)+tab)
// ---------------------------------------------------------------------------
__global__ __launch_bounds__(256) void k5_toff(const float* __restrict__ comp,
        const float* __restrict__ tw, const float* __restrict__ tb,
        const float* __restrict__ taw, const float* __restrict__ tab,
        float* __restrict__ toff)
{
    __shared__ __align__(16) float sw[64 * 16];
    for (int i = threadIdx.x; i < 64 * 16; i += 256) {
        int c = i >> 4, jj = i & 15;
        int oc = jj >> 1, kind = jj & 1;
        sw[i] = kind ? taw[oc * 64 + c] : tw[oc * 64 + c];
    }
    __syncthreads();
    int pix = blockIdx.x * 256 + threadIdx.x;
    int b = pix >> 14, hw = pix & 16383;
    float acc[16];
#pragma unroll
    for (int m = 0; m < 16; ++m) acc[m] = 0.f;
    const float* cp = comp + ((size_t)b * 64 << 14) + hw;
    for (int c = 0; c < 64; ++c) {
        float cv = cp[(size_t)c << 14];
        const float4* wr = reinterpret_cast<const float4*>(&sw[c << 4]);
#pragma unroll
        for (int m4 = 0; m4 < 4; ++m4) {
            float4 wv = wr[m4];
            acc[m4 * 4 + 0] += cv * wv.x; acc[m4 * 4 + 1] += cv * wv.y;
            acc[m4 * 4 + 2] += cv * wv.z; acc[m4 * 4 + 3] += cv * wv.w;
        }
    }
#pragma unroll
    for (int oc = 0; oc < 8; ++oc) {
        float o = acc[2 * oc]     + tb[oc];
        float a = acc[2 * oc + 1] + tab[oc];
        toff[((size_t)(b * 8 + oc) << 14) + hw] = o * (1.f / (1.f + expf(-a)));
    }
}

// ---------------------------------------------------------------------------
// K6: trim_op -> out. ix = w + ox clip[0,127]; thread per (b,g,h,w), 64 ch
// ---------------------------------------------------------------------------
__global__ __launch_bounds__(256) void k6_trim(const bf16* __restrict__ xfilt,
        const float* __restrict__ toff, float* __restrict__ out)
{
    int t = blockIdx.x * 256 + threadIdx.x;
    int w = t & 127, h = (t >> 7) & 127, g = (t >> 14) & 3, b = t >> 16;
    int hw = (h << 7) + w;
    float ox = toff[((size_t)(b * 8 + 2 * g)     << 14) + hw];
    float oy = toff[((size_t)(b * 8 + 2 * g + 1) << 14) + hw];
    float ix = fminf(fmaxf(w + ox, 0.f), 127.f);
    float iy = fminf(fmaxf(h + oy, 0.f), 127.f);
    float x0f = floorf(ix), y0f = floorf(iy);
    float fx = ix - x0f, fy = iy - y0f;
    int x0 = (int)x0f, y0 = (int)y0f;
    int x1 = min(x0 + 1, 127), y1 = min(y0 + 1, 127);
    float w00 = (1.f - fx) * (1.f - fy), w01 = fx * (1.f - fy);
    float w10 = (1.f - fx) * fy,        w11 = fx * fy;
    int i00 = (y0 << 7) + x0, i01 = (y0 << 7) + x1;
    int i10 = (y1 << 7) + x0, i11 = (y1 << 7) + x1;
    const bf16* xb = xfilt + ((size_t)(b * CC + (g << 6)) << 14);
    float* ob = out + ((size_t)(b * CC + (g << 6)) << 14) + hw;
    for (int c = 0; c < 64; ++c) {
        const bf16* xc = xb + ((size_t)c << 14);
        float v = w00 * b2f(xc[i00]) + w01 * b2f(xc[i01])
                + w10 * b2f(xc[i10]) + w11 * b2f(xc[i11]);
        ob[(size_t)c << 14] = v;
    }
}

extern "C" void kernel_launch(void* const* d_in, const int* in_sizes, int n_in,
                              void* d_out, int out_size, void* d_ws, size_t ws_size,
                              hipStream_t stream)
{
    const float* x       = (const float*)d_in[0];
    const float* w_off   = (const float*)d_in[1];
    const float* b_off   = (const float*)d_in[2];
    const float* w_ast   = (const float*)d_in[3];
    const float* b_ast   = (const float*)d_in[4];
    const float* comp_w  = (const float*)d_in[5];
    const float* comp_b  = (const float*)d_in[6];
    const float* filt_w  = (const float*)d_in[7];
    const float* filt_b  = (const float*)d_in[8];
    const float* trim_w  = (const float*)d_in[9];
    const float* trim_b  = (const float*)d_in[10];
    const float* trim_aw = (const float*)d_in[11];
    const float* trim_ab = (const float*)d_in[12];
    float* out = (float*)d_out;

    char* ws = (char*)d_ws;
    float* off   = (float*)(ws);                              // 2 MiB (dead after k2)
    bf16*  kern  = (bf16*) (ws);                              // 1.125 MiB, reuses off
    bf16*  xup   = (bf16*) (ws + (2ull << 20));               // 32 MiB
    float* comp  = (float*)(ws + (34ull << 20));              // 16 MiB
    bf16*  xfilt = (bf16*) (ws + (50ull << 20));              // 32 MiB
    float* toff  = (float*)(ws + (82ull << 20));              // 2 MiB (total 84 MiB)

    hipLaunchKernelGGL(k1_off,      dim3(256),   dim3(256), 0, stream,
                       x, w_off, b_off, w_ast, b_ast, off);
    hipLaunchKernelGGL(k2_defsample,dim3(1024),  dim3(256), 0, stream,
                       x, off, xup);
    hipLaunchKernelGGL(k3_comp,     dim3(1024),  dim3(256), 0, stream,
                       xup, comp_w, comp_b, comp);
    hipLaunchKernelGGL(k4a_kern,    dim3(256),   dim3(256), 0, stream,
                       comp, filt_w, filt_b, kern);
    hipLaunchKernelGGL(k4b_apply,   dim3(65536), dim3(256), 0, stream,
                       xup, kern, xfilt);
    hipLaunchKernelGGL(k5_toff,     dim3(256),   dim3(256), 0, stream,
                       comp, trim_w, trim_b, trim_aw, trim_ab, toff);
    hipLaunchKernelGGL(k6_trim,     dim3(1024),  dim3(256), 0, stream,
                       xfilt, toff, out);
}

// Round 4
// 271.234 us; speedup vs baseline: 2.2958x; 1.0290x over previous
//
#include <hip/hip_runtime.h>
#include <hip/hip_bf16.h>
#include <string.h>

typedef __hip_bfloat16 bf16;
typedef __attribute__((ext_vector_type(8))) short short8;
typedef __attribute__((ext_vector_type(4))) float f32x4;

__device__ __forceinline__ float b2f(bf16 v) { return __bfloat162float(v); }
__device__ __forceinline__ bf16  f2b(float v) { return __float2bfloat16(v); }
__device__ __forceinline__ float s2f(short s) {
    return __uint_as_float(((unsigned)(unsigned short)s) << 16);
}
__device__ __forceinline__ short f2s(float v) {
    bf16 t = f2b(v); short s; __builtin_memcpy(&s, &t, 2); return s;
}

// Problem sizes
#define CC 256
#define HWD 16384    // 128*128

// ---------------------------------------------------------------------------
// K1: off = (conv1x1(x, w_off)+b_off) * sigmoid(conv1x1(x, w_ast)+b_ast)
// off layout (b, 32, 4096) fp32
// ---------------------------------------------------------------------------
__global__ __launch_bounds__(256) void k1_off(const float* __restrict__ x,
        const float* __restrict__ w_off, const float* __restrict__ b_off,
        const float* __restrict__ w_ast, const float* __restrict__ b_ast,
        float* __restrict__ off)
{
    __shared__ __align__(16) float sw[256 * 16];
    const int q = blockIdx.x >> 6;
    const int pix = ((blockIdx.x & 63) << 8) + threadIdx.x;
    for (int i = threadIdx.x; i < 256 * 16; i += 256) {
        int c = i >> 4, jj = i & 15;
        int j = (q << 4) + jj;
        int oc = j >> 1, kind = j & 1;
        sw[i] = kind ? w_ast[oc * 256 + c] : w_off[oc * 256 + c];
    }
    __syncthreads();
    const int b = pix >> 12, hw = pix & 4095;
    float acc[16];
#pragma unroll
    for (int m = 0; m < 16; ++m) acc[m] = 0.f;
    const float* xp = x + ((size_t)b * CC << 12) + hw;
    for (int c = 0; c < 256; ++c) {
        float xv = xp[(size_t)c << 12];
        const float4* wrow = reinterpret_cast<const float4*>(&sw[c << 4]);
#pragma unroll
        for (int m4 = 0; m4 < 4; ++m4) {
            float4 wv = wrow[m4];
            acc[m4 * 4 + 0] += xv * wv.x; acc[m4 * 4 + 1] += xv * wv.y;
            acc[m4 * 4 + 2] += xv * wv.z; acc[m4 * 4 + 3] += xv * wv.w;
        }
    }
#pragma unroll
    for (int m = 0; m < 8; ++m) {
        int oc = (q << 3) + m;
        float o = acc[2 * m]     + b_off[oc];
        float a = acc[2 * m + 1] + b_ast[oc];
        float s = 1.f / (1.f + expf(-a));
        off[((size_t)(b * 32 + oc) << 12) + hw] = o * s;
    }
}

// ---------------------------------------------------------------------------
// K2: def_sample -> xup_pm (bf16, pixel-major (b, 16384, 256))
// thread per (b,g,hy,wx); gathers 64 channels, packs 8 at a time
// ---------------------------------------------------------------------------
__global__ __launch_bounds__(256) void k2_defsample(const float* __restrict__ x,
        const float* __restrict__ off, bf16* __restrict__ xup)
{
    int t = blockIdx.x * 256 + threadIdx.x;
    int wx = t & 127, hy = (t >> 7) & 127, g = (t >> 14) & 3, b = t >> 16;
    int h = hy >> 1, w = wx >> 1;
    int och = (g << 3) + ((hy & 1) << 2) + ((wx & 1) << 1);
    float ox = off[((size_t)(b * 32 + och)     << 12) + (h << 6) + w];
    float oy = off[((size_t)(b * 32 + och + 1) << 12) + (h << 6) + w];
    float ix = (wx + 0.5f + ox) * 0.5f - 0.5f;
    float iy = (hy + 0.5f + oy) * 0.5f - 0.5f;
    ix = fminf(fmaxf(ix, 0.f), 63.f);
    iy = fminf(fmaxf(iy, 0.f), 63.f);
    float x0f = floorf(ix), y0f = floorf(iy);
    float fx = ix - x0f, fy = iy - y0f;
    int x0 = (int)x0f, y0 = (int)y0f;
    int x1 = min(x0 + 1, 63), y1 = min(y0 + 1, 63);
    float w00 = (1.f - fx) * (1.f - fy), w01 = fx * (1.f - fy);
    float w10 = (1.f - fx) * fy,        w11 = fx * fy;
    int i00 = (y0 << 6) + x0, i01 = (y0 << 6) + x1;
    int i10 = (y1 << 6) + x0, i11 = (y1 << 6) + x1;
    const float* xb = x + ((size_t)(b * CC + (g << 6)) << 12);
    int hw = (hy << 7) + wx;
    short* orow = (short*)xup + ((size_t)(b * HWD + hw) << 8) + (g << 6);
    for (int c8 = 0; c8 < 8; ++c8) {
        short8 pk;
#pragma unroll
        for (int j = 0; j < 8; ++j) {
            const float* xc = xb + ((size_t)(c8 * 8 + j) << 12);
            float v = w00 * xc[i00] + w01 * xc[i01]
                    + w10 * xc[i10] + w11 * xc[i11];
            pk[j] = f2s(v);
        }
        *(short8*)(orow + c8 * 8) = pk;
    }
}

// ---------------------------------------------------------------------------
// K3: comp_pm[b][hw][64] = MFMA GEMM: xup_pm (65536x256 bf16) x cw^T (256x64)
// grid 1024: b = blk>>8, hw0 = (blk&255)*64. 4 waves; wave w owns oc [w*16,+16)
// B-frags (weights) preloaded to registers; A direct from global (L1 reuse)
// ---------------------------------------------------------------------------
__global__ __launch_bounds__(256) void k3_comp(const bf16* __restrict__ xup,
        const float* __restrict__ cw, const float* __restrict__ cb,
        float* __restrict__ comp)
{
    const int b = blockIdx.x >> 8;
    const int hw0 = (blockIdx.x & 255) << 6;
    const int lane = threadIdx.x & 63;
    const int n = lane & 15, quad = lane >> 4;
    const int ocb = (threadIdx.x >> 6) << 4;

    // preload B fragments: B[k][n] = cw[ocb+n][k], k = kc*32 + quad*8 + j
    short8 bfrag[8];
    const float* wrow = cw + (ocb + n) * 256 + quad * 8;
#pragma unroll
    for (int kc = 0; kc < 8; ++kc) {
        float4 lo = *(const float4*)(wrow + kc * 32);
        float4 hi = *(const float4*)(wrow + kc * 32 + 4);
        short8 f;
        f[0] = f2s(lo.x); f[1] = f2s(lo.y); f[2] = f2s(lo.z); f[3] = f2s(lo.w);
        f[4] = f2s(hi.x); f[5] = f2s(hi.y); f[6] = f2s(hi.z); f[7] = f2s(hi.w);
        bfrag[kc] = f;
    }
    float bias = cb[ocb + n];

    const short* abase = (const short*)xup + ((size_t)(b * HWD) << 8);
    float* cbase = comp + ((size_t)(b * HWD) << 6);

#pragma unroll
    for (int mt = 0; mt < 4; mt += 2) {
        f32x4 acc0 = {0.f, 0.f, 0.f, 0.f};
        f32x4 acc1 = {0.f, 0.f, 0.f, 0.f};
        const short8* ar0 = (const short8*)(abase + (((size_t)(hw0 + mt * 16 + n)) << 8) + quad * 8);
        const short8* ar1 = (const short8*)(abase + (((size_t)(hw0 + mt * 16 + 16 + n)) << 8) + quad * 8);
#pragma unroll
        for (int kc = 0; kc < 8; ++kc) {
            short8 a0 = ar0[kc * 4];
            short8 a1 = ar1[kc * 4];
            acc0 = __builtin_amdgcn_mfma_f32_16x16x32_bf16(a0, bfrag[kc], acc0, 0, 0, 0);
            acc1 = __builtin_amdgcn_mfma_f32_16x16x32_bf16(a1, bfrag[kc], acc1, 0, 0, 0);
        }
#pragma unroll
        for (int r = 0; r < 4; ++r) {
            int hwa = hw0 + mt * 16 + quad * 4 + r;
            cbase[((size_t)hwa << 6) + ocb + n] = acc0[r] + bias;
            cbase[((size_t)(hwa + 16) << 6) + ocb + n] = acc1[r] + bias;
        }
    }
}

// ---------------------------------------------------------------------------
// K4a: kern_pm[b][hw][16(pad)] = softmax(conv1x1(comp,64->9)+fb), bf16
// thread per pixel; comp rows contiguous
// ---------------------------------------------------------------------------
__global__ __launch_bounds__(256) void k4a_kern(const float* __restrict__ comp,
        const float* __restrict__ fw_g, const float* __restrict__ fb,
        bf16* __restrict__ kern)
{
    __shared__ __align__(16) float fw[64 * 12];
    for (int i = threadIdx.x; i < 64 * 12; i += 256) {
        int c = i / 12, k = i % 12;
        fw[i] = (k < 9) ? fw_g[k * 64 + c] : 0.f;
    }
    __syncthreads();
    int pix = blockIdx.x * 256 + threadIdx.x;
    int b = pix >> 14, hw = pix & 16383;
    float a[9];
#pragma unroll
    for (int k = 0; k < 9; ++k) a[k] = fb[k];
    const float4* row = (const float4*)(comp + ((size_t)(b * HWD + hw) << 6));
    for (int c4 = 0; c4 < 16; ++c4) {
        float4 cv = row[c4];
#pragma unroll
        for (int e = 0; e < 4; ++e) {
            int c = c4 * 4 + e;
            float v = (e == 0) ? cv.x : (e == 1) ? cv.y : (e == 2) ? cv.z : cv.w;
            const float4* wr = reinterpret_cast<const float4*>(&fw[c * 12]);
            float4 w0 = wr[0], w1 = wr[1];
            float w8 = fw[c * 12 + 8];
            a[0] += v * w0.x; a[1] += v * w0.y; a[2] += v * w0.z; a[3] += v * w0.w;
            a[4] += v * w1.x; a[5] += v * w1.y; a[6] += v * w1.z; a[7] += v * w1.w;
            a[8] += v * w8;
        }
    }
    float mx = a[0];
#pragma unroll
    for (int k = 1; k < 9; ++k) mx = fmaxf(mx, a[k]);
    float s = 0.f;
#pragma unroll
    for (int k = 0; k < 9; ++k) { a[k] = expf(a[k] - mx); s += a[k]; }
    float inv = 1.f / s;
    short* kr = (short*)kern + ((size_t)(b * HWD + hw) << 4);
    short8 pk;
#pragma unroll
    for (int k = 0; k < 8; ++k) pk[k] = f2s(a[k] * inv);
    *(short8*)kr = pk;
    kr[8] = f2s(a[8] * inv);
}

// ---------------------------------------------------------------------------
// K4b: xfilt_pm[b][hw][c] = sum_k kern[b][hw][k] * xup_pm[b][tap_k(hw)][c]
// thread per (b,hw,chunk of 8 channels): 2M threads, all 16B loads
// ---------------------------------------------------------------------------
__global__ __launch_bounds__(256) void k4b_apply(const bf16* __restrict__ xup,
        const bf16* __restrict__ kern, bf16* __restrict__ xfilt)
{
    int t = blockIdx.x * 256 + threadIdx.x;
    int chunk = t & 31;
    int hw = (t >> 5) & 16383;
    int b = t >> 19;
    int h = hw >> 7, w = hw & 127;

    const short* kr = (const short*)kern + ((size_t)(b * HWD + hw) << 4);
    short8 k8 = *(const short8*)kr;
    float wk[9];
#pragma unroll
    for (int k = 0; k < 8; ++k) wk[k] = s2f(k8[k]);
    wk[8] = s2f(kr[8]);

    float ymask[3] = { h > 0 ? 1.f : 0.f, 1.f, h < 127 ? 1.f : 0.f };
    float xmask[3] = { w > 0 ? 1.f : 0.f, 1.f, w < 127 ? 1.f : 0.f };
    int hy[3] = { (max(h - 1, 0)) << 7, h << 7, (min(h + 1, 127)) << 7 };
    int wx[3] = { max(w - 1, 0), w, min(w + 1, 127) };

    const short* xb = (const short*)xup + ((size_t)(b * HWD) << 8) + chunk * 8;
    float sum[8];
#pragma unroll
    for (int j = 0; j < 8; ++j) sum[j] = 0.f;
#pragma unroll
    for (int dy = 0; dy < 3; ++dy) {
#pragma unroll
        for (int dx = 0; dx < 3; ++dx) {
            float wgt = wk[dy * 3 + dx] * ymask[dy] * xmask[dx];
            short8 v = *(const short8*)(xb + ((size_t)(hy[dy] + wx[dx]) << 8));
#pragma unroll
            for (int j = 0; j < 8; ++j) sum[j] += wgt * s2f(v[j]);
        }
    }
    short8 pk;
#pragma unroll
    for (int j = 0; j < 8; ++j) pk[j] = f2s(sum[j]);
    *(short8*)((short*)xfilt + ((size_t)(b * HWD + hw) << 8) + chunk * 8) = pk;
}

// ---------------------------------------------------------------------------
// K5: toff = (conv1x1(comp,64->8)+tb) * sigmoid(conv1x1(comp,64->8)+tab)
// toff layout (b,8,16384) fp32; comp rows contiguous
// ---------------------------------------------------------------------------
__global__ __launch_bounds__(256) void k5_toff(const float* __restrict__ comp,
        const float* __restrict__ tw, const float* __restrict__ tb,
        const float* __restrict__ taw, const float* __restrict__ tab,
        float* __restrict__ toff)
{
    __shared__ __align__(16) float sw[64 * 16];
    for (int i = threadIdx.x; i < 64 * 16; i += 256) {
        int c = i >> 4, jj = i & 15;
        int oc = jj >> 1, kind = jj & 1;
        sw[i] = kind ? taw[oc * 64 + c] : tw[oc * 64 + c];
    }
    __syncthreads();
    int pix = blockIdx.x * 256 + threadIdx.x;
    int b = pix >> 14, hw = pix & 16383;
    float acc[16];
#pragma unroll
    for (int m = 0; m < 16; ++m) acc[m] = 0.f;
    const float4* row = (const float4*)(comp + ((size_t)(b * HWD + hw) << 6));
    for (int c4 = 0; c4 < 16; ++c4) {
        float4 cvv = row[c4];
#pragma unroll
        for (int e = 0; e < 4; ++e) {
            int c = c4 * 4 + e;
            float cv = (e == 0) ? cvv.x : (e == 1) ? cvv.y : (e == 2) ? cvv.z : cvv.w;
            const float4* wr = reinterpret_cast<const float4*>(&sw[c << 4]);
#pragma unroll
            for (int m4 = 0; m4 < 4; ++m4) {
                float4 wv = wr[m4];
                acc[m4 * 4 + 0] += cv * wv.x; acc[m4 * 4 + 1] += cv * wv.y;
                acc[m4 * 4 + 2] += cv * wv.z; acc[m4 * 4 + 3] += cv * wv.w;
            }
        }
    }
#pragma unroll
    for (int oc = 0; oc < 8; ++oc) {
        float o = acc[2 * oc]     + tb[oc];
        float a = acc[2 * oc + 1] + tab[oc];
        toff[((size_t)(b * 8 + oc) << 14) + hw] = o * (1.f / (1.f + expf(-a)));
    }
}

// ---------------------------------------------------------------------------
// K6: trim_op -> out (b,256,16384) fp32. thread per (b,g,hw), 8-ch chunks
// ---------------------------------------------------------------------------
__global__ __launch_bounds__(256) void k6_trim(const bf16* __restrict__ xfilt,
        const float* __restrict__ toff, float* __restrict__ out)
{
    int t = blockIdx.x * 256 + threadIdx.x;
    int w = t & 127, h = (t >> 7) & 127, g = (t >> 14) & 3, b = t >> 16;
    int hw = (h << 7) + w;
    float ox = toff[((size_t)(b * 8 + 2 * g)     << 14) + hw];
    float oy = toff[((size_t)(b * 8 + 2 * g + 1) << 14) + hw];
    float ix = fminf(fmaxf(w + ox, 0.f), 127.f);
    float iy = fminf(fmaxf(h + oy, 0.f), 127.f);
    float x0f = floorf(ix), y0f = floorf(iy);
    float fx = ix - x0f, fy = iy - y0f;
    int x0 = (int)x0f, y0 = (int)y0f;
    int x1 = min(x0 + 1, 127), y1 = min(y0 + 1, 127);
    float w00 = (1.f - fx) * (1.f - fy), w01 = fx * (1.f - fy);
    float w10 = (1.f - fx) * fy,        w11 = fx * fy;
    const short* base = (const short*)xfilt + ((size_t)(b * HWD) << 8) + (g << 6);
    const short* r00 = base + (((size_t)(y0 << 7) + x0) << 8);
    const short* r01 = base + (((size_t)(y0 << 7) + x1) << 8);
    const short* r10 = base + (((size_t)(y1 << 7) + x0) << 8);
    const short* r11 = base + (((size_t)(y1 << 7) + x1) << 8);
    float* ob = out + ((size_t)(b * CC + (g << 6)) << 14) + hw;
    for (int c8 = 0; c8 < 8; ++c8) {
        short8 v00 = *(const short8*)(r00 + c8 * 8);
        short8 v01 = *(const short8*)(r01 + c8 * 8);
        short8 v10 = *(const short8*)(r10 + c8 * 8);
        short8 v11 = *(const short8*)(r11 + c8 * 8);
#pragma unroll
        for (int j = 0; j < 8; ++j) {
            float v = w00 * s2f(v00[j]) + w01 * s2f(v01[j])
                    + w10 * s2f(v10[j]) + w11 * s2f(v11[j]);
            ob[(size_t)(c8 * 8 + j) << 14] = v;
        }
    }
}

extern "C" void kernel_launch(void* const* d_in, const int* in_sizes, int n_in,
                              void* d_out, int out_size, void* d_ws, size_t ws_size,
                              hipStream_t stream)
{
    const float* x       = (const float*)d_in[0];
    const float* w_off   = (const float*)d_in[1];
    const float* b_off   = (const float*)d_in[2];
    const float* w_ast   = (const float*)d_in[3];
    const float* b_ast   = (const float*)d_in[4];
    const float* comp_w  = (const float*)d_in[5];
    const float* comp_b  = (const float*)d_in[6];
    const float* filt_w  = (const float*)d_in[7];
    const float* filt_b  = (const float*)d_in[8];
    const float* trim_w  = (const float*)d_in[9];
    const float* trim_b  = (const float*)d_in[10];
    const float* trim_aw = (const float*)d_in[11];
    const float* trim_ab = (const float*)d_in[12];
    float* out = (float*)d_out;

    char* ws = (char*)d_ws;
    float* off   = (float*)(ws);                 // 2 MiB (dead after k2)
    bf16*  kern  = (bf16*) (ws);                 // 2 MiB, reuses off region
    bf16*  xup   = (bf16*) (ws + (2ull << 20));  // 32 MiB, pixel-major (b,hw,256)
    float* comp  = (float*)(ws + (34ull << 20)); // 16 MiB, pixel-major (b,hw,64)
    bf16*  xfilt = (bf16*) (ws + (50ull << 20)); // 32 MiB, pixel-major (b,hw,256)
    float* toff  = (float*)(ws + (82ull << 20)); // 2 MiB (total 84 MiB)

    hipLaunchKernelGGL(k1_off,      dim3(256),   dim3(256), 0, stream,
                       x, w_off, b_off, w_ast, b_ast, off);
    hipLaunchKernelGGL(k2_defsample,dim3(1024),  dim3(256), 0, stream,
                       x, off, xup);
    hipLaunchKernelGGL(k3_comp,     dim3(1024),  dim3(256), 0, stream,
                       xup, comp_w, comp_b, comp);
    hipLaunchKernelGGL(k4a_kern,    dim3(256),   dim3(256), 0, stream,
                       comp, filt_w, filt_b, kern);
    hipLaunchKernelGGL(k4b_apply,   dim3(8192),  dim3(256), 0, stream,
                       xup, kern, xfilt);
    hipLaunchKernelGGL(k5_toff,     dim3(256),   dim3(256), 0, stream,
                       comp, trim_w, trim_b, trim_aw, trim_ab, toff);
    hipLaunchKernelGGL(k6_trim,     dim3(1024),  dim3(256), 0, stream,
                       xfilt, toff, out);
}